// Round 4
// baseline (283.172 us; speedup 1.0000x reference)
//
#include <hip/hip_runtime.h>
#include <hip/hip_bf16.h>

// SDPA B=4 H=16 S=2048 D=64 fp32 I/O, key mask [B,1,1,S].
// Swapped-operand flash attention (m214 structure), 32x32x16 bf16 MFMA.
//   QK^T swapped: S^T = mfma(A=K, B=Q)  -> col = q = lane&31, row = key
//   PV  swapped: O^T = mfma(A=V^T, B=P) -> col = q = lane&31, row = d
// R4 additions: T14 async-STAGE (prefetch next K/V tile to regs, write LDS
// post-barrier), exp2-domain softmax (log2e folded into Q scale), T13
// defer-max (THR=8), tree max/sum reductions.

#define S_LEN 2048
#define D_DIM 64
#define KVB   64
#define QB    128   // q rows per block (4 waves x 32)
#define LDK   72    // padded LDS leading dim (bf16 elems)

typedef float  f32x16 __attribute__((ext_vector_type(16)));
typedef __bf16 bf8    __attribute__((ext_vector_type(8)));
typedef __bf16 bf4    __attribute__((ext_vector_type(4)));
typedef __bf16 bf2    __attribute__((ext_vector_type(2)));
typedef unsigned int u32x4 __attribute__((ext_vector_type(4)));

#define QSCALE (0.125f * 1.44269504088896340736f)   // 1/sqrt(64) * log2(e)

__global__ __launch_bounds__(256, 3)   // VGPR cap ~168; ~115 live expected
void sdpa_kernel(const float* __restrict__ q, const float* __restrict__ k,
                 const float* __restrict__ v, const int* __restrict__ mask,
                 float* __restrict__ out) {
    const int bh   = blockIdx.x;          // b*H + h
    const int qt   = blockIdx.y;          // q tile
    const int b    = bh >> 4;             // H = 16
    const int tid  = threadIdx.x;
    const int wave = tid >> 6;
    const int lane = tid & 63;
    const int l31  = lane & 31;
    const int hi   = lane >> 5;           // 0/1: which half-wave

    __shared__ __bf16 Kl[64 * LDK];       // K tile row-major [key][d]
    __shared__ __bf16 Vt[64 * LDK];       // V tile transposed [d][key]

    const size_t base = (size_t)bh * (S_LEN * D_DIM);

    // ---- staging geometry ----
    const int colg = (tid & 15) * 4;      // K: d column group
    const int row0 = tid >> 4;            // K: key row 0..15
    const int dd   = tid & 63;            // V: d
    const int kg   = (tid >> 6) * 16;     // V: key group

    float4 kx[4];                         // prefetched K (fp32)
    float  vx[16];                        // prefetched V (fp32)

    auto load_regs = [&](int kv0) {
        const float* kp = k + base + (size_t)(kv0 + row0) * D_DIM + colg;
        #pragma unroll
        for (int p = 0; p < 4; ++p)
            kx[p] = *(const float4*)(kp + (size_t)p * 16 * D_DIM);
        const float* vp = v + base + (size_t)(kv0 + kg) * D_DIM + dd;
        #pragma unroll
        for (int j = 0; j < 16; ++j)
            vx[j] = vp[(size_t)j * D_DIM];
    };
    auto store_lds = [&]() {
        #pragma unroll
        for (int p = 0; p < 4; ++p) {
            bf4 s;
            s[0] = (__bf16)kx[p].x; s[1] = (__bf16)kx[p].y;
            s[2] = (__bf16)kx[p].z; s[3] = (__bf16)kx[p].w;
            *(bf4*)(&Kl[(row0 + p * 16) * LDK + colg]) = s;
        }
        __bf16 tmp[16];
        #pragma unroll
        for (int j = 0; j < 16; ++j) tmp[j] = (__bf16)vx[j];
        *(bf8*)(&Vt[dd * LDK + kg])     = *(bf8*)(&tmp[0]);
        *(bf8*)(&Vt[dd * LDK + kg + 8]) = *(bf8*)(&tmp[8]);
    };

    // ---- Q fragment (B-operand): Q[q=qrow][d=ds*16+hi*8+e], scale folded ----
    const int qrow = qt * QB + wave * 32 + l31;
    bf8 qf[4];
    {
        const float* qp = q + base + (size_t)qrow * D_DIM;
        #pragma unroll
        for (int ds = 0; ds < 4; ++ds) {
            float4 a = *(const float4*)(qp + ds * 16 + hi * 8);
            float4 c = *(const float4*)(qp + ds * 16 + hi * 8 + 4);
            bf8 f;
            f[0] = (__bf16)(a.x * QSCALE); f[1] = (__bf16)(a.y * QSCALE);
            f[2] = (__bf16)(a.z * QSCALE); f[3] = (__bf16)(a.w * QSCALE);
            f[4] = (__bf16)(c.x * QSCALE); f[5] = (__bf16)(c.y * QSCALE);
            f[6] = (__bf16)(c.z * QSCALE); f[7] = (__bf16)(c.w * QSCALE);
            qf[ds] = f;
        }
    }

    f32x16 acc0 = (f32x16)0.0f;   // O^T, d 0..31
    f32x16 acc1 = (f32x16)0.0f;   // O^T, d 32..63
    float mrun = -INFINITY, lrun = 0.0f;

    // ---- prologue: stage tile 0 ----
    load_regs(0);
    store_lds();
    __syncthreads();

    for (int kv0 = 0; kv0 < S_LEN; kv0 += KVB) {
        const bool more = (kv0 + KVB < S_LEN);

        // mask load FIRST (oldest vmcnt slot), then prefetch (stays in flight)
        int mk = mask[b * S_LEN + kv0 + lane];
        if (more) load_regs(kv0 + KVB);
        unsigned long long bm = __ballot(mk != 0);

        // ---- QK^T swapped: p0 = S^T keys 0..31, p1 = keys 32..63 (log2 units) ----
        f32x16 p0 = (f32x16)0.0f, p1 = (f32x16)0.0f;
        #pragma unroll
        for (int ds = 0; ds < 4; ++ds) {
            bf8 k0 = *(const bf8*)(&Kl[l31 * LDK        + ds * 16 + hi * 8]);
            bf8 k1 = *(const bf8*)(&Kl[(32 + l31) * LDK + ds * 16 + hi * 8]);
            p0 = __builtin_amdgcn_mfma_f32_32x32x16_bf16(k0, qf[ds], p0, 0, 0, 0);
            p1 = __builtin_amdgcn_mfma_f32_32x32x16_bf16(k1, qf[ds], p1, 0, 0, 0);
        }

        if (bm != ~0ull) {   // wave-uniform skip for the all-ones mask
            #pragma unroll
            for (int r = 0; r < 16; ++r) {
                int kr = (r & 3) + 8 * (r >> 2) + 4 * hi;
                if (!((bm >> kr) & 1))        p0[r] = -1e9f;
                if (!((bm >> (32 + kr)) & 1)) p1[r] = -1e9f;
            }
        }

        // ---- tree max over the lane's 32 scores + partner exchange ----
        float tt[16];
        #pragma unroll
        for (int r = 0; r < 16; ++r) tt[r] = fmaxf(p0[r], p1[r]);
        #pragma unroll
        for (int r = 0; r < 8; ++r) tt[r] = fmaxf(tt[r], tt[r + 8]);
        #pragma unroll
        for (int r = 0; r < 4; ++r) tt[r] = fmaxf(tt[r], tt[r + 4]);
        float mx = fmaxf(fmaxf(tt[0], tt[1]), fmaxf(tt[2], tt[3]));
        mx = fmaxf(mx, __shfl_xor(mx, 32));

        // ---- T13 defer-max: only rescale when max grew > 8 (log2 units) ----
        if (!__all(mx - mrun <= 8.0f)) {
            float mnew = fmaxf(mrun, mx);
            float sc = __builtin_amdgcn_exp2f(mrun - mnew);
            lrun *= sc;
            #pragma unroll
            for (int r = 0; r < 16; ++r) { acc0[r] *= sc; acc1[r] *= sc; }
            mrun = mnew;
        }

        float rsp[4] = {0.0f, 0.0f, 0.0f, 0.0f};
        // ---- per 32-key block: exp2, bf16-pack, half-wave exchange, PV ----
        auto do_kb = [&](f32x16& p, int kbbase) {
            #pragma unroll
            for (int r = 0; r < 16; ++r) {
                p[r] = __builtin_amdgcn_exp2f(p[r] - mrun);
                rsp[r & 3] += p[r];
            }
            // lo lane holds keys {0-3,8-11,16-19,24-27}, hi holds +4.
            unsigned wds[8], xw[8];
            #pragma unroll
            for (int j = 0; j < 8; ++j) {
                bf2 t; t[0] = (__bf16)p[2 * j]; t[1] = (__bf16)p[2 * j + 1];
                wds[j] = __builtin_bit_cast(unsigned, t);
            }
            #pragma unroll
            for (int j = 0; j < 8; ++j)
                xw[j] = (unsigned)__shfl_xor((int)wds[j], 32);
            #pragma unroll
            for (int ks = 0; ks < 2; ++ks) {
                // B-frag: keys kbbase + ks*16 + hi*8 + 0..7 of this q-row
                u32x4 uu;
                uu[0] = hi ? xw[4 * ks + 2]  : wds[4 * ks + 0];
                uu[1] = hi ? xw[4 * ks + 3]  : wds[4 * ks + 1];
                uu[2] = hi ? wds[4 * ks + 2] : xw[4 * ks + 0];
                uu[3] = hi ? wds[4 * ks + 3] : xw[4 * ks + 1];
                bf8 pf = __builtin_bit_cast(bf8, uu);
                bf8 v0 = *(const bf8*)(&Vt[l31 * LDK        + kbbase + ks * 16 + hi * 8]);
                bf8 v1 = *(const bf8*)(&Vt[(32 + l31) * LDK + kbbase + ks * 16 + hi * 8]);
                acc0 = __builtin_amdgcn_mfma_f32_32x32x16_bf16(v0, pf, acc0, 0, 0, 0);
                acc1 = __builtin_amdgcn_mfma_f32_32x32x16_bf16(v1, pf, acc1, 0, 0, 0);
            }
        };
        do_kb(p0, 0);
        do_kb(p1, 32);
        float rs = (rsp[0] + rsp[1]) + (rsp[2] + rsp[3]);
        rs += __shfl_xor(rs, 32);
        lrun += rs;

        // ---- T14 write-late: all waves done reading LDS, then restage ----
        if (more) {
            __syncthreads();
            store_lds();          // compiler inserts vmcnt waits for kx/vx
            __syncthreads();
        }
    }

    // ---- epilogue: O[q][d] = acc[d][q]/l ; reg r -> d = (r&3)+8*(r>>2)+4*hi ----
    float inv = 1.0f / lrun;
    float* op = out + base + (size_t)qrow * D_DIM;
    #pragma unroll
    for (int g = 0; g < 4; ++g) {
        int d0 = g * 8 + hi * 4;
        float4 s0, s1;
        s0.x = acc0[4 * g + 0] * inv; s0.y = acc0[4 * g + 1] * inv;
        s0.z = acc0[4 * g + 2] * inv; s0.w = acc0[4 * g + 3] * inv;
        s1.x = acc1[4 * g + 0] * inv; s1.y = acc1[4 * g + 1] * inv;
        s1.z = acc1[4 * g + 2] * inv; s1.w = acc1[4 * g + 3] * inv;
        *(float4*)(op + d0)      = s0;
        *(float4*)(op + 32 + d0) = s1;
    }
}

extern "C" void kernel_launch(void* const* d_in, const int* in_sizes, int n_in,
                              void* d_out, int out_size, void* d_ws, size_t ws_size,
                              hipStream_t stream) {
    (void)in_sizes; (void)n_in; (void)d_ws; (void)ws_size; (void)out_size;
    const float* q    = (const float*)d_in[0];
    const float* k    = (const float*)d_in[1];
    const float* v    = (const float*)d_in[2];
    const int*   mask = (const int*)d_in[3];
    // d_in[4] = dropout, identity in eval reference.
    float* out = (float*)d_out;

    dim3 grid(64, 16);
    dim3 block(256);
    sdpa_kernel<<<grid, block, 0, stream>>>(q, k, v, mask, out);
}

// Round 6
// 240.763 us; speedup vs baseline: 1.1761x; 1.1761x over previous
//
#include <hip/hip_runtime.h>
#include <hip/hip_bf16.h>

// SDPA B=4 H=16 S=2048 D=64 fp32 I/O, key mask [B,1,1,S].
// Swapped-operand flash attention (m214 structure), 32x32x16 bf16 MFMA.
//   QK^T swapped: S^T = mfma(A=K, B=Q)  -> col = q = lane&31, row = key
//   PV  swapped: O^T = mfma(A=V^T, B=P) -> col = q = lane&31, row = d
// R6 (= R5 resubmit; infra failure): LDS double-buffer, ONE barrier/tile;
// prefetch-early/write-late (T14) with launch_bounds(256,2) so prefetch regs
// do NOT spill (R4 bug: WRITE_SIZE +38MB scratch). exp2 softmax + defer-max
// + tree reductions kept.

#define S_LEN 2048
#define D_DIM 64
#define KVB   64
#define QB    128   // q rows per block (4 waves x 32)
#define LDK   72    // padded LDS leading dim (bf16): 144B stride, 0 conflicts (R3 measured)

typedef float  f32x16 __attribute__((ext_vector_type(16)));
typedef __bf16 bf8    __attribute__((ext_vector_type(8)));
typedef __bf16 bf4    __attribute__((ext_vector_type(4)));
typedef __bf16 bf2    __attribute__((ext_vector_type(2)));
typedef unsigned int u32x4 __attribute__((ext_vector_type(4)));

#define QSCALE (0.125f * 1.44269504088896340736f)   // 1/sqrt(64) * log2(e)

__global__ __launch_bounds__(256, 2)   // VGPR cap 256: prefetch must stay in regs
void sdpa_kernel(const float* __restrict__ q, const float* __restrict__ k,
                 const float* __restrict__ v, const int* __restrict__ mask,
                 float* __restrict__ out) {
    const int bh   = blockIdx.x;          // b*H + h
    const int qt   = blockIdx.y;          // q tile
    const int b    = bh >> 4;             // H = 16
    const int tid  = threadIdx.x;
    const int wave = tid >> 6;
    const int lane = tid & 63;
    const int l31  = lane & 31;
    const int hi   = lane >> 5;           // 0/1: which half-wave

    // double-buffered tiles
    __shared__ __bf16 Kl[2][64 * LDK];
    __shared__ __bf16 Vt[2][64 * LDK];

    const size_t base = (size_t)bh * (S_LEN * D_DIM);

    // ---- staging geometry ----
    const int colg = (tid & 15) * 4;      // K: d column group
    const int row0 = tid >> 4;            // K: key row 0..15
    const int dd   = tid & 63;            // V: d
    const int kg   = (tid >> 6) * 16;     // V: key group

    float4 kx[4];                         // prefetched K (fp32)
    float  vx[16];                        // prefetched V (fp32)

    auto load_regs = [&](int kv0) {
        const float* kp = k + base + (size_t)(kv0 + row0) * D_DIM + colg;
        #pragma unroll
        for (int p = 0; p < 4; ++p)
            kx[p] = *(const float4*)(kp + (size_t)p * 16 * D_DIM);
        const float* vp = v + base + (size_t)(kv0 + kg) * D_DIM + dd;
        #pragma unroll
        for (int j = 0; j < 16; ++j)
            vx[j] = vp[(size_t)j * D_DIM];
    };
    auto store_lds = [&](int pb) {
        #pragma unroll
        for (int p = 0; p < 4; ++p) {
            bf4 s;
            s[0] = (__bf16)kx[p].x; s[1] = (__bf16)kx[p].y;
            s[2] = (__bf16)kx[p].z; s[3] = (__bf16)kx[p].w;
            *(bf4*)(&Kl[pb][(row0 + p * 16) * LDK + colg]) = s;
        }
        __bf16 tmp[16];
        #pragma unroll
        for (int j = 0; j < 16; ++j) tmp[j] = (__bf16)vx[j];
        *(bf8*)(&Vt[pb][dd * LDK + kg])     = *(bf8*)(&tmp[0]);
        *(bf8*)(&Vt[pb][dd * LDK + kg + 8]) = *(bf8*)(&tmp[8]);
    };

    // ---- Q fragment (B-operand): Q[q=qrow][d=ds*16+hi*8+e], scale folded ----
    const int qrow = qt * QB + wave * 32 + l31;
    bf8 qf[4];
    {
        const float* qp = q + base + (size_t)qrow * D_DIM;
        #pragma unroll
        for (int ds = 0; ds < 4; ++ds) {
            float4 a = *(const float4*)(qp + ds * 16 + hi * 8);
            float4 c = *(const float4*)(qp + ds * 16 + hi * 8 + 4);
            bf8 f;
            f[0] = (__bf16)(a.x * QSCALE); f[1] = (__bf16)(a.y * QSCALE);
            f[2] = (__bf16)(a.z * QSCALE); f[3] = (__bf16)(a.w * QSCALE);
            f[4] = (__bf16)(c.x * QSCALE); f[5] = (__bf16)(c.y * QSCALE);
            f[6] = (__bf16)(c.z * QSCALE); f[7] = (__bf16)(c.w * QSCALE);
            qf[ds] = f;
        }
    }

    f32x16 acc0 = (f32x16)0.0f;   // O^T, d 0..31
    f32x16 acc1 = (f32x16)0.0f;   // O^T, d 32..63
    float mrun = -INFINITY, lrun = 0.0f;

    // ---- prologue: stage tile 0 into buffer 0 ----
    load_regs(0);
    store_lds(0);
    __syncthreads();

    int par = 0;
    for (int kv0 = 0; kv0 < S_LEN; kv0 += KVB) {
        const bool more = (kv0 + KVB < S_LEN);

        // mask load first (oldest vmcnt slot), then prefetch next tile
        int mk = mask[b * S_LEN + kv0 + lane];
        if (more) load_regs(kv0 + KVB);
        unsigned long long bm = __ballot(mk != 0);

        const __bf16* Kb = &Kl[par][0];
        const __bf16* Vb = &Vt[par][0];

        // ---- QK^T swapped: p0 = S^T keys 0..31, p1 = keys 32..63 (log2 units) ----
        f32x16 p0 = (f32x16)0.0f, p1 = (f32x16)0.0f;
        #pragma unroll
        for (int ds = 0; ds < 4; ++ds) {
            bf8 k0 = *(const bf8*)(&Kb[l31 * LDK        + ds * 16 + hi * 8]);
            bf8 k1 = *(const bf8*)(&Kb[(32 + l31) * LDK + ds * 16 + hi * 8]);
            p0 = __builtin_amdgcn_mfma_f32_32x32x16_bf16(k0, qf[ds], p0, 0, 0, 0);
            p1 = __builtin_amdgcn_mfma_f32_32x32x16_bf16(k1, qf[ds], p1, 0, 0, 0);
        }

        if (bm != ~0ull) {   // wave-uniform skip for the all-ones mask
            #pragma unroll
            for (int r = 0; r < 16; ++r) {
                int kr = (r & 3) + 8 * (r >> 2) + 4 * hi;
                if (!((bm >> kr) & 1))        p0[r] = -1e9f;
                if (!((bm >> (32 + kr)) & 1)) p1[r] = -1e9f;
            }
        }

        // ---- tree max over the lane's 32 scores + partner exchange ----
        float tt[16];
        #pragma unroll
        for (int r = 0; r < 16; ++r) tt[r] = fmaxf(p0[r], p1[r]);
        #pragma unroll
        for (int r = 0; r < 8; ++r) tt[r] = fmaxf(tt[r], tt[r + 8]);
        #pragma unroll
        for (int r = 0; r < 4; ++r) tt[r] = fmaxf(tt[r], tt[r + 4]);
        float mx = fmaxf(fmaxf(tt[0], tt[1]), fmaxf(tt[2], tt[3]));
        mx = fmaxf(mx, __shfl_xor(mx, 32));

        // ---- T13 defer-max: rescale only when max grew > 8 (log2 units) ----
        if (!__all(mx - mrun <= 8.0f)) {
            float mnew = fmaxf(mrun, mx);
            float sc = __builtin_amdgcn_exp2f(mrun - mnew);
            lrun *= sc;
            #pragma unroll
            for (int r = 0; r < 16; ++r) { acc0[r] *= sc; acc1[r] *= sc; }
            mrun = mnew;
        }

        float rsp[4] = {0.0f, 0.0f, 0.0f, 0.0f};
        // ---- per 32-key block: exp2, bf16-pack, half-wave exchange, PV ----
        auto do_kb = [&](f32x16& p, int kbbase) {
            #pragma unroll
            for (int r = 0; r < 16; ++r) {
                p[r] = __builtin_amdgcn_exp2f(p[r] - mrun);
                rsp[r & 3] += p[r];
            }
            // lo lane holds keys {0-3,8-11,16-19,24-27}, hi holds +4.
            unsigned wds[8], xw[8];
            #pragma unroll
            for (int j = 0; j < 8; ++j) {
                bf2 t; t[0] = (__bf16)p[2 * j]; t[1] = (__bf16)p[2 * j + 1];
                wds[j] = __builtin_bit_cast(unsigned, t);
            }
            #pragma unroll
            for (int j = 0; j < 8; ++j)
                xw[j] = (unsigned)__shfl_xor((int)wds[j], 32);
            #pragma unroll
            for (int ks = 0; ks < 2; ++ks) {
                // B-frag: keys kbbase + ks*16 + hi*8 + 0..7 of this q-row
                u32x4 uu;
                uu[0] = hi ? xw[4 * ks + 2]  : wds[4 * ks + 0];
                uu[1] = hi ? xw[4 * ks + 3]  : wds[4 * ks + 1];
                uu[2] = hi ? wds[4 * ks + 2] : xw[4 * ks + 0];
                uu[3] = hi ? wds[4 * ks + 3] : xw[4 * ks + 1];
                bf8 pf = __builtin_bit_cast(bf8, uu);
                bf8 v0 = *(const bf8*)(&Vb[l31 * LDK        + kbbase + ks * 16 + hi * 8]);
                bf8 v1 = *(const bf8*)(&Vb[(32 + l31) * LDK + kbbase + ks * 16 + hi * 8]);
                acc0 = __builtin_amdgcn_mfma_f32_32x32x16_bf16(v0, pf, acc0, 0, 0, 0);
                acc1 = __builtin_amdgcn_mfma_f32_32x32x16_bf16(v1, pf, acc1, 0, 0, 0);
            }
        };
        do_kb(p0, 0);
        do_kb(p1, 32);
        float rs = (rsp[0] + rsp[1]) + (rsp[2] + rsp[3]);
        rs += __shfl_xor(rs, 32);
        lrun += rs;

        // ---- write-late into the other buffer; ONE barrier per tile ----
        // Barrier also licenses tile t+2's overwrite of buf[par] (all reads done).
        if (more) {
            store_lds(par ^ 1);   // compiler inserts vmcnt waits for kx/vx
            __syncthreads();
            par ^= 1;
        }
    }

    // ---- epilogue: O[q][d] = acc[d][q]/l ; reg r -> d = (r&3)+8*(r>>2)+4*hi ----
    float inv = 1.0f / lrun;
    float* op = out + base + (size_t)qrow * D_DIM;
    #pragma unroll
    for (int g = 0; g < 4; ++g) {
        int d0 = g * 8 + hi * 4;
        float4 s0, s1;
        s0.x = acc0[4 * g + 0] * inv; s0.y = acc0[4 * g + 1] * inv;
        s0.z = acc0[4 * g + 2] * inv; s0.w = acc0[4 * g + 3] * inv;
        s1.x = acc1[4 * g + 0] * inv; s1.y = acc1[4 * g + 1] * inv;
        s1.z = acc1[4 * g + 2] * inv; s1.w = acc1[4 * g + 3] * inv;
        *(float4*)(op + d0)      = s0;
        *(float4*)(op + 32 + d0) = s1;
    }
}

extern "C" void kernel_launch(void* const* d_in, const int* in_sizes, int n_in,
                              void* d_out, int out_size, void* d_ws, size_t ws_size,
                              hipStream_t stream) {
    (void)in_sizes; (void)n_in; (void)d_ws; (void)ws_size; (void)out_size;
    const float* q    = (const float*)d_in[0];
    const float* k    = (const float*)d_in[1];
    const float* v    = (const float*)d_in[2];
    const int*   mask = (const int*)d_in[3];
    // d_in[4] = dropout, identity in eval reference.
    float* out = (float*)d_out;

    dim3 grid(64, 16);
    dim3 block(256);
    sdpa_kernel<<<grid, block, 0, stream>>>(q, k, v, mask, out);
}